// Round 1
// baseline (248.786 us; speedup 1.0000x reference)
//
#include <hip/hip_runtime.h>

#define B_ 8
#define L_ 4096
#define H_ 8
#define E_ 64
#define NEIGH_ 128
#define SPLITS_ 32
#define BQ 128        // queries per block
#define WIN 256       // key window per block
#define QPAD 72       // 64 + 8 pad (bf16 elems)
#define VPAD 264      // 256 + 8 pad (bf16 elems)

typedef float f32x4 __attribute__((ext_vector_type(4)));
typedef __bf16 bf16x8 __attribute__((ext_vector_type(8)));
typedef unsigned short u16x4 __attribute__((ext_vector_type(4)));
typedef unsigned short u16x8 __attribute__((ext_vector_type(8)));

__device__ inline unsigned short f2bf(float f) {
  unsigned int u = __float_as_uint(f);
  u += 0x7fff + ((u >> 16) & 1);   // RNE
  return (unsigned short)(u >> 16);
}

__global__ __launch_bounds__(512) void la_kernel(
    const float* __restrict__ Q, const float* __restrict__ K,
    const float* __restrict__ V, float* __restrict__ out) {
  const int j = blockIdx.x, h = blockIdx.y, b = blockIdx.z;
  const int t = threadIdx.x;

  __shared__ unsigned short Qs[BQ * QPAD];    // 18,432 B
  __shared__ unsigned short Ks[WIN * QPAD];   // 36,864 B
  __shared__ unsigned short VsT[E_ * VPAD];   // 33,792 B  (V transposed: [e][key])
  __shared__ unsigned short Ps[BQ * VPAD];    // 67,584 B  -> total 156,672 B

  const int q0 = j * BQ;
  const int g0 = q0 - NEIGH_;   // global key index of window position 0

  // ---- stage Q (coalesced float4, cvt to bf16) ----
  for (int i = 0; i < 4; ++i) {
    int idx = t + i * 512;                 // 0..2047
    int row = idx >> 4, c4 = idx & 15;
    const float4 v = *(const float4*)(Q + ((((size_t)b * L_) + q0 + row) * H_ + h) * E_ + c4 * 4);
    u16x4 p = { f2bf(v.x), f2bf(v.y), f2bf(v.z), f2bf(v.w) };
    *(u16x4*)&Qs[row * QPAD + c4 * 4] = p;
  }
  // ---- stage K ----
  for (int i = 0; i < 8; ++i) {
    int idx = t + i * 512;                 // 0..4095
    int km = idx >> 4, c4 = idx & 15;
    int g = g0 + km; g = g < 0 ? 0 : g;    // clamp (masked anyway)
    const float4 v = *(const float4*)(K + ((((size_t)b * L_) + g) * H_ + h) * E_ + c4 * 4);
    u16x4 p = { f2bf(v.x), f2bf(v.y), f2bf(v.z), f2bf(v.w) };
    *(u16x4*)&Ks[km * QPAD + c4 * 4] = p;
  }
  // ---- stage V transposed: VsT[e][km] ----
  for (int i = 0; i < 8; ++i) {
    int idx = t + i * 512;
    int km = idx >> 4, c4 = idx & 15;
    int g = g0 + km; g = g < 0 ? 0 : g;
    const float4 v = *(const float4*)(V + ((((size_t)b * L_) + g) * H_ + h) * E_ + c4 * 4);
    VsT[(c4 * 4 + 0) * VPAD + km] = f2bf(v.x);
    VsT[(c4 * 4 + 1) * VPAD + km] = f2bf(v.y);
    VsT[(c4 * 4 + 2) * VPAD + km] = f2bf(v.z);
    VsT[(c4 * 4 + 3) * VPAD + km] = f2bf(v.w);
  }
  __syncthreads();

  const int wv = t >> 6, lane = t & 63;
  const int l15 = lane & 15, quad = lane >> 4;
  const int r0 = wv * 16;    // wave's first query row (16 rows per wave)

  // ---- S = Q K^T : 16 key-tiles of 16x16, K-dim = 64 in 2 steps ----
  f32x4 S[16];
  for (int kt = 0; kt < 16; ++kt) S[kt] = (f32x4){0.f, 0.f, 0.f, 0.f};
  for (int ks = 0; ks < 2; ++ks) {
    // A[m=lane&15][k=quad*8+jj]: Q row r0+l15, e = ks*32 + quad*8 ..+7
    bf16x8 a = __builtin_bit_cast(bf16x8,
        *(const u16x8*)&Qs[(r0 + l15) * QPAD + ks * 32 + quad * 8]);
    for (int kt = 0; kt < 16; ++kt) {
      // B[k][n=lane&15] = K[key=kt*16+l15][e=ks*32+quad*8+jj]
      bf16x8 bb = __builtin_bit_cast(bf16x8,
          *(const u16x8*)&Ks[(kt * 16 + l15) * QPAD + ks * 32 + quad * 8]);
      S[kt] = __builtin_amdgcn_mfma_f32_16x16x32_bf16(a, bb, S[kt], 0, 0, 0);
    }
  }

  // ---- mask + scale, row max (C/D layout: col=lane&15, row=quad*4+reg) ----
  float mrow[4] = {-1e30f, -1e30f, -1e30f, -1e30f};
  for (int kt = 0; kt < 16; ++kt) {
    int key = kt * 16 + l15;
    for (int r = 0; r < 4; ++r) {
      int lq = r0 + quad * 4 + r;
      float s = S[kt][r] * 0.125f;
      bool valid = (key > lq) & (key <= lq + NEIGH_) & (g0 + key >= 0);
      s = valid ? s : -1e30f;
      S[kt][r] = s;
      mrow[r] = fmaxf(mrow[r], s);
    }
  }
#pragma unroll
  for (int m = 1; m <= 8; m <<= 1)
    for (int r = 0; r < 4; ++r)
      mrow[r] = fmaxf(mrow[r], __shfl_xor(mrow[r], m));

  // ---- exp + row sum + write unnormalized P to LDS (bf16) ----
  float lrow[4] = {0.f, 0.f, 0.f, 0.f};
  for (int kt = 0; kt < 16; ++kt) {
    int key = kt * 16 + l15;
    for (int r = 0; r < 4; ++r) {
      float p = __expf(S[kt][r] - mrow[r]);   // masked: exp(-1e30)=0
      lrow[r] += p;
      Ps[(r0 + quad * 4 + r) * VPAD + key] = f2bf(p);
    }
  }
#pragma unroll
  for (int m = 1; m <= 8; m <<= 1)
    for (int r = 0; r < 4; ++r)
      lrow[r] += __shfl_xor(lrow[r], m);
  float inv[4];
  for (int r = 0; r < 4; ++r) inv[r] = 1.0f / lrow[r];

  __syncthreads();

  // ---- O = P V : 4 e-tiles, K-dim = 256 in 8 steps ----
  f32x4 O[4];
  for (int et = 0; et < 4; ++et) O[et] = (f32x4){0.f, 0.f, 0.f, 0.f};
  for (int ks = 0; ks < 8; ++ks) {
    bf16x8 a = __builtin_bit_cast(bf16x8,
        *(const u16x8*)&Ps[(r0 + l15) * VPAD + ks * 32 + quad * 8]);
    for (int et = 0; et < 4; ++et) {
      // B[k=key][n=e]: VsT[e=et*16+l15][key=ks*32+quad*8+jj]
      bf16x8 bb = __builtin_bit_cast(bf16x8,
          *(const u16x8*)&VsT[(et * 16 + l15) * VPAD + ks * 32 + quad * 8]);
      O[et] = __builtin_amdgcn_mfma_f32_16x16x32_bf16(a, bb, O[et], 0, 0, 0);
    }
  }

  // ---- store (normalize by 1/l) ----
  for (int et = 0; et < 4; ++et)
    for (int r = 0; r < 4; ++r) {
      int row = r0 + quad * 4 + r;
      int e = et * 16 + l15;
      out[((((size_t)b * L_) + q0 + row) * H_ + h) * E_ + e] = O[et][r] * inv[r];
    }
}

extern "C" void kernel_launch(void* const* d_in, const int* in_sizes, int n_in,
                              void* d_out, int out_size, void* d_ws, size_t ws_size,
                              hipStream_t stream) {
  const float* q = (const float*)d_in[0];
  const float* k = (const float*)d_in[1];
  const float* v = (const float*)d_in[2];
  float* o = (float*)d_out;
  dim3 grid(SPLITS_, H_, B_);   // 32 x 8 x 8 = 2048 blocks
  la_kernel<<<grid, 512, 0, stream>>>(q, k, v, o);
}

// Round 2
// 221.868 us; speedup vs baseline: 1.1213x; 1.1213x over previous
//
#include <hip/hip_runtime.h>

#define B_ 8
#define L_ 4096
#define H_ 8
#define E_ 64
#define NEIGH_ 128
#define SPLITS_ 32
#define BQ 128        // queries per block
#define WIN 256       // key window per block
#define KPAD 72       // 64 + 8 pad (bf16 elems) for Ks rows

typedef float f32x4 __attribute__((ext_vector_type(4)));
typedef __bf16 bf16x8 __attribute__((ext_vector_type(8)));
typedef unsigned short u16x4 __attribute__((ext_vector_type(4)));
typedef unsigned short u16x8 __attribute__((ext_vector_type(8)));
typedef unsigned int u32;

__device__ inline unsigned short f2bf(float f) {
  unsigned int u = __float_as_uint(f);
  u += 0x7fff + ((u >> 16) & 1);   // RNE
  return (unsigned short)(u >> 16);
}
__device__ inline u32 pack2(float a, float b) {
  return (u32)f2bf(a) | ((u32)f2bf(b) << 16);
}

// S^T formulation: S^T[key][q] = K·Q^T. C-layout: q = lane&15, key = quad*4+reg.
// P transforms C->A layout via bpermute (no LDS round-trip).
__global__ __launch_bounds__(512, 4) void la_kernel(
    const float* __restrict__ Q, const float* __restrict__ K,
    const float* __restrict__ V, float* __restrict__ out) {
  const int j = blockIdx.x, h = blockIdx.y, b = blockIdx.z;
  const int t = threadIdx.x;

  __shared__ unsigned short Ks[WIN * KPAD];  // 36,864 B
  __shared__ u32 Vs32[E_ * (WIN / 2)];       // 32,768 B  VsT [e][key], XOR-swizzled 8-key groups
  // total 69,632 B -> 2 blocks/CU

  const int q0 = j * BQ;
  const int g0 = q0 - NEIGH_;   // global key index of window position 0

  // ---- stage K (coalesced float4 -> bf16) ----
  for (int i = 0; i < 8; ++i) {
    int idx = t + i * 512;                 // 0..4095
    int km = idx >> 4, c4 = idx & 15;
    int g = g0 + km; g = g < 0 ? 0 : g;    // clamp (masked later)
    const float4 v = *(const float4*)(K + ((((size_t)b * L_) + g) * H_ + h) * E_ + c4 * 4);
    u16x4 p = { f2bf(v.x), f2bf(v.y), f2bf(v.z), f2bf(v.w) };
    *(u16x4*)&Ks[km * KPAD + c4 * 4] = p;
  }
  // ---- stage V transposed [e][key] with XOR-group swizzle, pair-packed b32 writes ----
  for (int i = 0; i < 4; ++i) {
    int idx = t + i * 512;                 // 0..2047
    int kp = idx >> 4, c4 = idx & 15;      // key pair 0..127, col group 0..15
    int k0g = g0 + 2 * kp, k1g = k0g + 1;
    k0g = k0g < 0 ? 0 : k0g; k1g = k1g < 0 ? 0 : k1g;
    const float4 v0 = *(const float4*)(V + ((((size_t)b * L_) + k0g) * H_ + h) * E_ + c4 * 4);
    const float4 v1 = *(const float4*)(V + ((((size_t)b * L_) + k1g) * H_ + h) * E_ + c4 * 4);
    int g = kp >> 2;                       // 8-key group 0..31
    int ko = kp & 3;                       // u32 offset within group (2 keys per u32)
    const float a0[4] = {v0.x, v0.y, v0.z, v0.w};
    const float a1[4] = {v1.x, v1.y, v1.z, v1.w};
#pragma unroll
    for (int w = 0; w < 4; ++w) {
      int e = c4 * 4 + w;
      int gs = g ^ (e & 31);               // swizzled group
      Vs32[e * 128 + gs * 4 + ko] = pack2(a0[w], a1[w]);
    }
  }

  const int wv = t >> 6, lane = t & 63;
  const int l15 = lane & 15, quad = lane >> 4;
  const int r0 = wv * 16;    // wave's first query row (16 per wave)
  const int lq = r0 + l15;   // this lane's query (local index 0..127)

  // ---- Q B-fragment direct from global: B[k=e][n=q]: row q0+lq, e = ks*32+quad*8+jj ----
  bf16x8 qfrag[2];
  {
    const float* qrow = Q + ((((size_t)b * L_) + q0 + lq) * H_ + h) * E_;
#pragma unroll
    for (int ks = 0; ks < 2; ++ks) {
      const float4 x = *(const float4*)(qrow + ks * 32 + quad * 8);
      const float4 y = *(const float4*)(qrow + ks * 32 + quad * 8 + 4);
      u16x8 p = { f2bf(x.x), f2bf(x.y), f2bf(x.z), f2bf(x.w),
                  f2bf(y.x), f2bf(y.y), f2bf(y.z), f2bf(y.w) };
      qfrag[ks] = __builtin_bit_cast(bf16x8, p);
    }
  }
  __syncthreads();

  // ---- S^T = K Q^T : 16 key-tiles, K-dim 64 in 2 steps. A=K rows, B=Q^T ----
  f32x4 S[16];
#pragma unroll
  for (int kt = 0; kt < 16; ++kt) S[kt] = (f32x4){0.f, 0.f, 0.f, 0.f};
#pragma unroll
  for (int ks = 0; ks < 2; ++ks) {
#pragma unroll
    for (int kt = 0; kt < 16; ++kt) {
      bf16x8 a = __builtin_bit_cast(bf16x8,
          *(const u16x8*)&Ks[(kt * 16 + l15) * KPAD + ks * 32 + quad * 8]);
      S[kt] = __builtin_amdgcn_mfma_f32_16x16x32_bf16(a, qfrag[ks], S[kt], 0, 0, 0);
    }
  }

  // ---- scale + mask + row max (one query row per lane: q = l15) ----
  float m = -1e30f;
#pragma unroll
  for (int kt = 0; kt < 16; ++kt) {
#pragma unroll
    for (int r = 0; r < 4; ++r) {
      int key = kt * 16 + quad * 4 + r;
      float s = S[kt][r] * 0.125f;
      bool valid = (key > lq) & (key <= lq + NEIGH_) & (g0 + key >= 0);
      s = valid ? s : -1e30f;
      S[kt][r] = s;
      m = fmaxf(m, s);
    }
  }
  m = fmaxf(m, __shfl_xor(m, 16));
  m = fmaxf(m, __shfl_xor(m, 32));

  // ---- exp + row sum; pack P to bf16 pairs (C-layout regs (0,1),(2,3)) ----
  float lsum = 0.f;
  u32 pk[16][2];
#pragma unroll
  for (int kt = 0; kt < 16; ++kt) {
    float p0 = __expf(S[kt][0] - m);
    float p1 = __expf(S[kt][1] - m);
    float p2 = __expf(S[kt][2] - m);
    float p3 = __expf(S[kt][3] - m);
    lsum += (p0 + p1) + (p2 + p3);
    pk[kt][0] = pack2(p0, p1);
    pk[kt][1] = pack2(p2, p3);
  }
  lsum += __shfl_xor(lsum, 16);
  lsum += __shfl_xor(lsum, 32);
  const float inv = 1.0f / lsum;

  // ---- O = P V : A = P via register transpose (bpermute), B = VsT swizzled ----
  f32x4 O[4];
#pragma unroll
  for (int et = 0; et < 4; ++et) O[et] = (f32x4){0.f, 0.f, 0.f, 0.f};
  const int srcBase = 16 * ((quad & 1) * 2) + l15;   // + 16*(k>>1)
  const bool hiTile = (quad >> 1) != 0;
#pragma unroll
  for (int ks = 0; ks < 8; ++ks) {
    u32 a32[4];
#pragma unroll
    for (int k = 0; k < 4; ++k) {
      int src = srcBase + 16 * (k >> 1);
      u32 u0 = (u32)__shfl((int)pk[2 * ks][k & 1], src);
      u32 u1 = (u32)__shfl((int)pk[2 * ks + 1][k & 1], src);
      a32[k] = hiTile ? u1 : u0;
    }
    bf16x8 afrag = __builtin_bit_cast(bf16x8,
        (u32 __attribute__((ext_vector_type(4)))){a32[0], a32[1], a32[2], a32[3]});
#pragma unroll
    for (int et = 0; et < 4; ++et) {
      int e = et * 16 + l15;
      int gs = (ks * 4 + quad) ^ (e & 31);
      bf16x8 bfrag = __builtin_bit_cast(bf16x8,
          *(const u16x8*)((const unsigned short*)Vs32 + e * 256 + gs * 8));
      O[et] = __builtin_amdgcn_mfma_f32_16x16x32_bf16(afrag, bfrag, O[et], 0, 0, 0);
    }
  }

  // ---- store: O C-layout row = q = quad*4+r, col = e = et*16+l15 ----
  float invq[4];
#pragma unroll
  for (int r = 0; r < 4; ++r) invq[r] = __shfl(inv, quad * 4 + r);
#pragma unroll
  for (int et = 0; et < 4; ++et)
#pragma unroll
    for (int r = 0; r < 4; ++r) {
      int row = r0 + quad * 4 + r;
      out[((((size_t)b * L_) + q0 + row) * H_ + h) * E_ + et * 16 + l15] = O[et][r] * invq[r];
    }
}

extern "C" void kernel_launch(void* const* d_in, const int* in_sizes, int n_in,
                              void* d_out, int out_size, void* d_ws, size_t ws_size,
                              hipStream_t stream) {
  const float* q = (const float*)d_in[0];
  const float* k = (const float*)d_in[1];
  const float* v = (const float*)d_in[2];
  float* o = (float*)d_out;
  dim3 grid(SPLITS_, H_, B_);   // 2048 blocks
  la_kernel<<<grid, 512, 0, stream>>>(q, k, v, o);
}